// Round 5
// baseline (260.715 us; speedup 1.0000x reference)
//
#include <hip/hip_runtime.h>
#include <hip/hip_cooperative_groups.h>

namespace cg = cooperative_groups;

#define H     2048
#define UD    1280        // [du(256), u(1024)]
#define NT    4           // Taylor matvec steps; trunc err ~3e-8 rel
#define RPB   8           // rows of A per block
#define NBLK  (H / RPB)   // 256 blocks == 256 CUs, co-resident
#define DELTAF 0.1f

// ws float offsets (tiny: 5 vectors)
#define OFF_XH0 0
#define OFF_XH1 (OFF_XH0 + H)
#define OFF_XB0 (OFF_XH1 + H)
#define OFF_XB1 (OFF_XB0 + H)
#define OFF_HS  (OFF_XB1 + H)

// One cooperative kernel does everything:
//  phase 0: block b stages W rows [8b,8b+8) to LDS, computes bu rows,
//           antisymmetrizes in place: A[j][c] = 0.5*(W[8b+j][c] - W[c][8b+j])
//  phase 1: NT Taylor steps, dual chain (E*h and 0.1*phi1(0.1A)*bu),
//           x vectors ping-pong through ws, grid.sync between steps
//  phase 2: y = C @ (s1+s2), wave per output row
__global__ __launch_bounds__(256) void cte_coop(
    const float* __restrict__ W, const float* __restrict__ Bw,
    const float* __restrict__ Cw, const float* __restrict__ u,
    const float* __restrict__ du, const float* __restrict__ h,
    float* __restrict__ ws, float* __restrict__ out)
{
    extern __shared__ float Asl[];        // RPB x H = 64 KB
    float4* Af4 = (float4*)Asl;
    cg::grid_group grid = cg::this_grid();

    const int b    = blockIdx.x;
    const int tid  = threadIdx.x;
    const int lane = tid & 63;
    const int w    = tid >> 6;            // wave 0..3
    const int rl0  = 2 * w, rl1 = 2 * w + 1;   // local A rows owned by wave

    // ---- stage W rows into LDS (coalesced float4) ----
    {
        const float4* Wb = (const float4*)(W + (size_t)b * RPB * H);
        #pragma unroll
        for (int r = 0; r < RPB; ++r) {
            Af4[r * 512 + tid]       = Wb[r * 512 + tid];
            Af4[r * 512 + 256 + tid] = Wb[r * 512 + 256 + tid];
        }
    }

    // ---- bu = B @ [du,u] for the wave's two rows; init running sums ----
    float s1[2], s2[2], q0[2];
    {
        const int rls[2] = {rl0, rl1};
        #pragma unroll
        for (int t = 0; t < 2; ++t) {
            const int gr = b * RPB + rls[t];
            const float4* Brow = (const float4*)(Bw + (size_t)gr * UD);
            float acc = 0.f;
            #pragma unroll
            for (int i = 0; i < 5; ++i) {
                int f = i * 64 + lane;
                float4 xv = (f < 64) ? ((const float4*)du)[f]
                                     : ((const float4*)u)[f - 64];
                float4 bb = Brow[f];
                acc = fmaf(bb.x, xv.x, acc);
                acc = fmaf(bb.y, xv.y, acc);
                acc = fmaf(bb.z, xv.z, acc);
                acc = fmaf(bb.w, xv.w, acc);
            }
            #pragma unroll
            for (int off = 32; off; off >>= 1) acc += __shfl_xor(acc, off, 64);
            q0[t] = DELTAF * acc;         // q_0 = 0.1 * bu
            s2[t] = q0[t];
            s1[t] = h[gr];                // term_0 = h
        }
    }

    __syncthreads();   // W rows fully in LDS

    // ---- antisymmetrize vs column panel W[:, 8b:8b+8) ----
    #pragma unroll
    for (int kk = 0; kk < 8; ++kk) {
        const int c = kk * 256 + tid;
        const float* Wc = W + (size_t)c * H + b * RPB;
        float4 w0 = *(const float4*)(Wc);
        float4 w1 = *(const float4*)(Wc + 4);
        Asl[0 * H + c] = 0.5f * (Asl[0 * H + c] - w0.x);
        Asl[1 * H + c] = 0.5f * (Asl[1 * H + c] - w0.y);
        Asl[2 * H + c] = 0.5f * (Asl[2 * H + c] - w0.z);
        Asl[3 * H + c] = 0.5f * (Asl[3 * H + c] - w0.w);
        Asl[4 * H + c] = 0.5f * (Asl[4 * H + c] - w1.x);
        Asl[5 * H + c] = 0.5f * (Asl[5 * H + c] - w1.y);
        Asl[6 * H + c] = 0.5f * (Asl[6 * H + c] - w1.z);
        Asl[7 * H + c] = 0.5f * (Asl[7 * H + c] - w1.w);
    }

    // publish q0 as xb chain input
    if (lane == 0) {
        ws[OFF_XB0 + b * RPB + rl0] = q0[0];
        ws[OFF_XB0 + b * RPB + rl1] = q0[1];
    }

    grid.sync();   // xb0 visible; also covers this block's LDS completion

    // ---- Taylor loop: x_{k+1} = c * (A x_k), dual chain ----
    float* xhb[2] = {ws + OFF_XH0, ws + OFF_XH1};
    float* xbb[2] = {ws + OFF_XB0, ws + OFF_XB1};

    #pragma unroll
    for (int k = 0; k < NT; ++k) {
        const int si = k & 1, di = si ^ 1;
        const float cH = DELTAF / (float)(k + 1);
        const float cB = DELTAF / (float)(k + 2);
        const float4* Xh = (const float4*)((k == 0) ? h : xhb[si]);
        const float4* Xb = (const float4*)xbb[si];

        float4 vh[8], vb[8];
        #pragma unroll
        for (int i = 0; i < 8; ++i) {
            vh[i] = Xh[i * 64 + lane];
            vb[i] = Xb[i * 64 + lane];
        }

        const int rls[2] = {rl0, rl1};
        #pragma unroll
        for (int t = 0; t < 2; ++t) {
            const float4* Ar = Af4 + rls[t] * 512;
            float ah = 0.f, ab = 0.f;
            #pragma unroll
            for (int i = 0; i < 8; ++i) {
                float4 a = Ar[i * 64 + lane];
                ah = fmaf(a.x, vh[i].x, ah); ab = fmaf(a.x, vb[i].x, ab);
                ah = fmaf(a.y, vh[i].y, ah); ab = fmaf(a.y, vb[i].y, ab);
                ah = fmaf(a.z, vh[i].z, ah); ab = fmaf(a.z, vb[i].z, ab);
                ah = fmaf(a.w, vh[i].w, ah); ab = fmaf(a.w, vb[i].w, ab);
            }
            #pragma unroll
            for (int off = 32; off; off >>= 1) {
                ah += __shfl_xor(ah, off, 64);
                ab += __shfl_xor(ab, off, 64);
            }
            const float nh = cH * ah, nb = cB * ab;
            s1[t] += nh; s2[t] += nb;
            if (lane == 0) {
                const int gr = b * RPB + rls[t];
                if (k < NT - 1) { xhb[di][gr] = nh; xbb[di][gr] = nb; }
                else            { ws[OFF_HS + gr] = s1[t] + s2[t]; }
            }
        }
        grid.sync();
    }

    // ---- y = C @ hsum: block b -> rows [4b,4b+4), wave per row ----
    {
        const int row = b * 4 + w;
        const float4* Crow = (const float4*)(Cw + (size_t)row * H);
        const float4* Hs   = (const float4*)(ws + OFF_HS);
        float acc = 0.f;
        #pragma unroll
        for (int i = 0; i < 8; ++i) {
            float4 c4 = Crow[i * 64 + lane];
            float4 hv = Hs[i * 64 + lane];
            acc = fmaf(c4.x, hv.x, acc);
            acc = fmaf(c4.y, hv.y, acc);
            acc = fmaf(c4.z, hv.z, acc);
            acc = fmaf(c4.w, hv.w, acc);
        }
        #pragma unroll
        for (int off = 32; off; off >>= 1) acc += __shfl_xor(acc, off, 64);
        if (lane == 0) out[row] = acc;
    }
}

// ---------------------------------------------------------------------------
extern "C" void kernel_launch(void* const* d_in, const int* in_sizes, int n_in,
                              void* d_out, int out_size, void* d_ws, size_t ws_size,
                              hipStream_t stream) {
    const float* u  = (const float*)d_in[0];
    const float* du = (const float*)d_in[1];
    const float* W  = (const float*)d_in[2];
    const float* Bw = (const float*)d_in[3];
    const float* Cw = (const float*)d_in[4];
    const float* h  = (const float*)d_in[5];
    float* ws  = (float*)d_ws;
    float* out = (float*)d_out;

    void* args[] = {(void*)&W, (void*)&Bw, (void*)&Cw, (void*)&u,
                    (void*)&du, (void*)&h, (void*)&ws, (void*)&out};
    hipLaunchCooperativeKernel((const void*)cte_coop, dim3(NBLK), dim3(256),
                               args, RPB * H * sizeof(float), stream);
}

// Round 6
// 104.220 us; speedup vs baseline: 2.5016x; 2.5016x over previous
//
#include <hip/hip_runtime.h>
#include <hip/hip_fp16.h>

// Sizes (fixed per reference)
#define H    2048
#define UD   1280   // [du(256), u(1024)]
#define NT   3      // Taylor steps: trunc err ~1e-7 rel, << 0.0078 ref-fp32 floor

typedef __attribute__((ext_vector_type(8))) _Float16 half8;

// ws layout: A as fp16 [H*H] at byte 0 (8.4 MB), then fp32 vectors.
#define OFF_F_BASE ((size_t)H * H / 2)   // float index after fp16 A
#define OFF_XH0 (OFF_F_BASE)
#define OFF_XH1 (OFF_XH0 + H)
#define OFF_XB0 (OFF_XH1 + H)
#define OFF_XB1 (OFF_XB0 + H)
#define OFF_S1  (OFF_XB1 + H)
#define OFF_S2  (OFF_S1 + H)

#define NTILE     (H / 64)                  // 32
#define NPAIRS    (NTILE * (NTILE + 1) / 2) // 528
#define BU_BLOCKS 512

// ---------------------------------------------------------------------------
// Fused: blocks [0,528) build A = 0.5*(W - W^T) as fp16 (64x64 tile pairs, W
// read exactly once); blocks [528,1040) compute bu = B@[du,u] and init chains.
__global__ __launch_bounds__(256) void build_init(const float* __restrict__ W,
                                                  const float* __restrict__ Bw,
                                                  const float* __restrict__ u,
                                                  const float* __restrict__ du,
                                                  const float* __restrict__ h,
                                                  float* __restrict__ ws) {
    if (blockIdx.x < NPAIRS) {
        __half* Ah = (__half*)ws;
        int p = blockIdx.x;
        int ti = 0, rowlen = NTILE;
        while (p >= rowlen) { p -= rowlen; ++ti; --rowlen; }
        int tj = ti + p;

        __shared__ float t1[64][65];
        __shared__ float t2[64][65];
        const int tx = threadIdx.x & 63, ty = threadIdx.x >> 6;
        const int r0 = ti * 64, c0 = tj * 64;

        for (int r = ty; r < 64; r += 4) {
            t1[r][tx] = W[(size_t)(r0 + r) * H + c0 + tx];
            t2[r][tx] = W[(size_t)(c0 + r) * H + r0 + tx];
        }
        __syncthreads();
        for (int r = ty; r < 64; r += 4) {
            Ah[(size_t)(r0 + r) * H + c0 + tx] =
                __float2half(0.5f * (t1[r][tx] - t2[tx][r]));
            if (ti != tj)
                Ah[(size_t)(c0 + r) * H + r0 + tx] =
                    __float2half(0.5f * (t2[r][tx] - t1[tx][r]));
        }
    } else {
        float* xh0 = ws + OFF_XH0;
        float* xb0 = ws + OFF_XB0;
        float* s1  = ws + OFF_S1;
        float* s2  = ws + OFF_S2;

        const int bid  = blockIdx.x - NPAIRS;             // [0,512)
        const int gt   = bid * 256 + threadIdx.x;
        const int lane = threadIdx.x & 63;
        const int r    = bid * 4 + (threadIdx.x >> 6);    // B row [0,2048)

        if (gt < H) { float hv = h[gt]; xh0[gt] = hv; s1[gt] = hv; }

        const float4* Brow = (const float4*)(Bw + (size_t)r * UD);
        float acc = 0.f;
        #pragma unroll
        for (int i = 0; i < 5; ++i) {
            int f = i * 64 + lane;
            float4 xv = (f < 64) ? ((const float4*)du)[f] : ((const float4*)u)[f - 64];
            float4 b = Brow[f];
            acc = fmaf(b.x, xv.x, acc);
            acc = fmaf(b.y, xv.y, acc);
            acc = fmaf(b.z, xv.z, acc);
            acc = fmaf(b.w, xv.w, acc);
        }
        #pragma unroll
        for (int off = 32; off; off >>= 1) acc += __shfl_xor(acc, off, 64);
        if (lane == 0) { float v = 0.1f * acc; xb0[r] = v; s2[r] = v; }
    }
}

// ---------------------------------------------------------------------------
// Dual-chain matvec on fp16 A: x_out = c*(A x_in); s += x_out.
// Block = 4 waves = (2 rows x 2 K-halves); LDS combine. 1024 blocks.
__global__ __launch_bounds__(256) void matvec(const __half* __restrict__ A,
                                              const float4* __restrict__ xhin,
                                              const float4* __restrict__ xbin,
                                              float* __restrict__ xhout,
                                              float* __restrict__ xbout,
                                              float* __restrict__ s1,
                                              float* __restrict__ s2,
                                              float cH, float cB) {
    const int tid  = threadIdx.x;
    const int lane = tid & 63;
    const int w    = tid >> 6;
    const int rl   = w >> 1;          // local row
    const int hf   = w & 1;           // K-half
    const int r    = blockIdx.x * 2 + rl;

    const half8* Arow = (const half8*)(A + (size_t)r * H);
    float ah = 0.f, ab = 0.f;
    #pragma unroll
    for (int i = 0; i < 2; ++i) {
        int g = hf * 128 + i * 64 + lane;   // half8 index: cols 8g..8g+7
        half8 a = Arow[g];
        float4 xh0 = xhin[2 * g],     xb0 = xbin[2 * g];
        float4 xh1 = xhin[2 * g + 1], xb1 = xbin[2 * g + 1];
        float a0 = (float)a[0], a1 = (float)a[1], a2 = (float)a[2], a3 = (float)a[3];
        float a4 = (float)a[4], a5 = (float)a[5], a6 = (float)a[6], a7 = (float)a[7];
        ah = fmaf(a0, xh0.x, ah); ab = fmaf(a0, xb0.x, ab);
        ah = fmaf(a1, xh0.y, ah); ab = fmaf(a1, xb0.y, ab);
        ah = fmaf(a2, xh0.z, ah); ab = fmaf(a2, xb0.z, ab);
        ah = fmaf(a3, xh0.w, ah); ab = fmaf(a3, xb0.w, ab);
        ah = fmaf(a4, xh1.x, ah); ab = fmaf(a4, xb1.x, ab);
        ah = fmaf(a5, xh1.y, ah); ab = fmaf(a5, xb1.y, ab);
        ah = fmaf(a6, xh1.z, ah); ab = fmaf(a6, xb1.z, ab);
        ah = fmaf(a7, xh1.w, ah); ab = fmaf(a7, xb1.w, ab);
    }
    #pragma unroll
    for (int off = 32; off; off >>= 1) {
        ah += __shfl_xor(ah, off, 64);
        ab += __shfl_xor(ab, off, 64);
    }

    __shared__ float ph[4], pb[4];
    if (lane == 0) { ph[w] = ah; pb[w] = ab; }
    __syncthreads();
    if (tid < 2) {
        int rr = blockIdx.x * 2 + tid;
        float nh = cH * (ph[tid * 2] + ph[tid * 2 + 1]);
        float nb = cB * (pb[tid * 2] + pb[tid * 2 + 1]);
        xhout[rr] = nh; xbout[rr] = nb;
        s1[rr] += nh;   s2[rr] += nb;   // exclusive row owner
    }
}

// ---------------------------------------------------------------------------
// y = C @ (s1 + s2); block = 4 waves = (2 rows x 2 K-halves). 512 blocks.
__global__ __launch_bounds__(256) void final_y(const float* __restrict__ C,
                                               const float* __restrict__ ws,
                                               float* __restrict__ out) {
    const float4* s14 = (const float4*)(ws + OFF_S1);
    const float4* s24 = (const float4*)(ws + OFF_S2);
    const int tid  = threadIdx.x;
    const int lane = tid & 63;
    const int w    = tid >> 6;
    const int rl   = w >> 1;
    const int hf   = w & 1;
    const int r    = blockIdx.x * 2 + rl;

    const float4* Crow = (const float4*)(C + (size_t)r * H);
    float acc = 0.f;
    #pragma unroll
    for (int i = 0; i < 4; ++i) {
        int f = hf * 256 + i * 64 + lane;
        float4 c = Crow[f];
        float4 a = s14[f], b = s24[f];
        acc = fmaf(c.x, a.x + b.x, acc);
        acc = fmaf(c.y, a.y + b.y, acc);
        acc = fmaf(c.z, a.z + b.z, acc);
        acc = fmaf(c.w, a.w + b.w, acc);
    }
    #pragma unroll
    for (int off = 32; off; off >>= 1) acc += __shfl_xor(acc, off, 64);

    __shared__ float pr[4];
    if (lane == 0) pr[w] = acc;
    __syncthreads();
    if (tid < 2) out[blockIdx.x * 2 + tid] = pr[tid * 2] + pr[tid * 2 + 1];
}

// ---------------------------------------------------------------------------
extern "C" void kernel_launch(void* const* d_in, const int* in_sizes, int n_in,
                              void* d_out, int out_size, void* d_ws, size_t ws_size,
                              hipStream_t stream) {
    const float* u  = (const float*)d_in[0];
    const float* du = (const float*)d_in[1];
    const float* W  = (const float*)d_in[2];
    const float* Bw = (const float*)d_in[3];
    const float* Cw = (const float*)d_in[4];
    const float* h  = (const float*)d_in[5];
    float* ws  = (float*)d_ws;
    float* out = (float*)d_out;

    build_init<<<NPAIRS + BU_BLOCKS, 256, 0, stream>>>(W, Bw, u, du, h, ws);

    const __half* Ah = (const __half*)d_ws;
    float* xh[2] = {ws + OFF_XH0, ws + OFF_XH1};
    float* xb[2] = {ws + OFF_XB0, ws + OFF_XB1};
    for (int k = 0; k < NT; ++k) {
        int a = k & 1, b = a ^ 1;
        matvec<<<1024, 256, 0, stream>>>(Ah,
                                         (const float4*)xh[a], (const float4*)xb[a],
                                         xh[b], xb[b],
                                         ws + OFF_S1, ws + OFF_S2,
                                         0.1f / (float)(k + 1), 0.1f / (float)(k + 2));
    }
    final_y<<<512, 256, 0, stream>>>(Cw, ws, out);
}

// Round 8
// 99.906 us; speedup vs baseline: 2.6096x; 1.0432x over previous
//
#include <hip/hip_runtime.h>
#include <hip/hip_fp16.h>

// Sizes (fixed per reference)
#define H    2048
#define UD   1280   // [du(256), u(1024)]
#define NT   2      // Taylor steps: trunc err ~2e-4 worst-case on y, << 0.0078 ref floor

typedef __attribute__((ext_vector_type(8))) _Float16 half8;

// ws layout: A as fp16 [H*H] at byte 0 (8.4 MB), then fp32 vectors.
#define OFF_F_BASE ((size_t)H * H / 2)   // float index after fp16 A
#define OFF_XH0 (OFF_F_BASE)
#define OFF_XH1 (OFF_XH0 + H)
#define OFF_XB0 (OFF_XH1 + H)
#define OFF_XB1 (OFF_XB0 + H)
#define OFF_S1  (OFF_XB1 + H)
#define OFF_S2  (OFF_S1 + H)

#define NTILE     (H / 64)                  // 32
#define NPAIRS    (NTILE * (NTILE + 1) / 2) // 528
#define BU_BLOCKS 512

// ---------------------------------------------------------------------------
// Fused: blocks [0,528) build A = 0.5*(W - W^T) as fp16 (64x64 tile pairs, W
// read exactly once); blocks [528,1040) compute bu = B@[du,u] and init chains.
__global__ __launch_bounds__(256) void build_init(const float* __restrict__ W,
                                                  const float* __restrict__ Bw,
                                                  const float* __restrict__ u,
                                                  const float* __restrict__ du,
                                                  const float* __restrict__ h,
                                                  float* __restrict__ ws) {
    if (blockIdx.x < NPAIRS) {
        __half* Ah = (__half*)ws;
        int p = blockIdx.x;
        int ti = 0, rowlen = NTILE;
        while (p >= rowlen) { p -= rowlen; ++ti; --rowlen; }
        int tj = ti + p;

        __shared__ float t1[64][65];
        __shared__ float t2[64][65];
        const int tx = threadIdx.x & 63, ty = threadIdx.x >> 6;
        const int r0 = ti * 64, c0 = tj * 64;

        for (int r = ty; r < 64; r += 4) {
            t1[r][tx] = W[(size_t)(r0 + r) * H + c0 + tx];
            t2[r][tx] = W[(size_t)(c0 + r) * H + r0 + tx];
        }
        __syncthreads();
        for (int r = ty; r < 64; r += 4) {
            Ah[(size_t)(r0 + r) * H + c0 + tx] =
                __float2half(0.5f * (t1[r][tx] - t2[tx][r]));
            if (ti != tj)
                Ah[(size_t)(c0 + r) * H + r0 + tx] =
                    __float2half(0.5f * (t2[r][tx] - t1[tx][r]));
        }
    } else {
        float* xh0 = ws + OFF_XH0;
        float* xb0 = ws + OFF_XB0;
        float* s1  = ws + OFF_S1;
        float* s2  = ws + OFF_S2;

        const int bid  = blockIdx.x - NPAIRS;             // [0,512)
        const int gt   = bid * 256 + threadIdx.x;
        const int lane = threadIdx.x & 63;
        const int r    = bid * 4 + (threadIdx.x >> 6);    // B row [0,2048)

        if (gt < H) { float hv = h[gt]; xh0[gt] = hv; s1[gt] = hv; }

        const float4* Brow = (const float4*)(Bw + (size_t)r * UD);
        float acc = 0.f;
        #pragma unroll
        for (int i = 0; i < 5; ++i) {
            int f = i * 64 + lane;
            float4 xv = (f < 64) ? ((const float4*)du)[f] : ((const float4*)u)[f - 64];
            float4 b = Brow[f];
            acc = fmaf(b.x, xv.x, acc);
            acc = fmaf(b.y, xv.y, acc);
            acc = fmaf(b.z, xv.z, acc);
            acc = fmaf(b.w, xv.w, acc);
        }
        #pragma unroll
        for (int off = 32; off; off >>= 1) acc += __shfl_xor(acc, off, 64);
        if (lane == 0) { float v = 0.1f * acc; xb0[r] = v; s2[r] = v; }
    }
}

// ---------------------------------------------------------------------------
// Dual-chain matvec on fp16 A: x_out = c*(A x_in); s += x_out.
// Block = 4 waves = (2 rows x 2 K-halves); LDS combine. 1024 blocks.
__global__ __launch_bounds__(256) void matvec(const __half* __restrict__ A,
                                              const float4* __restrict__ xhin,
                                              const float4* __restrict__ xbin,
                                              float* __restrict__ xhout,
                                              float* __restrict__ xbout,
                                              float* __restrict__ s1,
                                              float* __restrict__ s2,
                                              float cH, float cB) {
    const int tid  = threadIdx.x;
    const int lane = tid & 63;
    const int w    = tid >> 6;
    const int rl   = w >> 1;          // local row
    const int hf   = w & 1;           // K-half
    const int r    = blockIdx.x * 2 + rl;

    const half8* Arow = (const half8*)(A + (size_t)r * H);
    float ah = 0.f, ab = 0.f;
    #pragma unroll
    for (int i = 0; i < 2; ++i) {
        int g = hf * 128 + i * 64 + lane;   // half8 index: cols 8g..8g+7
        half8 a = Arow[g];
        float4 xh0 = xhin[2 * g],     xb0 = xbin[2 * g];
        float4 xh1 = xhin[2 * g + 1], xb1 = xbin[2 * g + 1];
        float a0 = (float)a[0], a1 = (float)a[1], a2 = (float)a[2], a3 = (float)a[3];
        float a4 = (float)a[4], a5 = (float)a[5], a6 = (float)a[6], a7 = (float)a[7];
        ah = fmaf(a0, xh0.x, ah); ab = fmaf(a0, xb0.x, ab);
        ah = fmaf(a1, xh0.y, ah); ab = fmaf(a1, xb0.y, ab);
        ah = fmaf(a2, xh0.z, ah); ab = fmaf(a2, xb0.z, ab);
        ah = fmaf(a3, xh0.w, ah); ab = fmaf(a3, xb0.w, ab);
        ah = fmaf(a4, xh1.x, ah); ab = fmaf(a4, xb1.x, ab);
        ah = fmaf(a5, xh1.y, ah); ab = fmaf(a5, xb1.y, ab);
        ah = fmaf(a6, xh1.z, ah); ab = fmaf(a6, xb1.z, ab);
        ah = fmaf(a7, xh1.w, ah); ab = fmaf(a7, xb1.w, ab);
    }
    #pragma unroll
    for (int off = 32; off; off >>= 1) {
        ah += __shfl_xor(ah, off, 64);
        ab += __shfl_xor(ab, off, 64);
    }

    __shared__ float ph[4], pb[4];
    if (lane == 0) { ph[w] = ah; pb[w] = ab; }
    __syncthreads();
    if (tid < 2) {
        int rr = blockIdx.x * 2 + tid;
        float nh = cH * (ph[tid * 2] + ph[tid * 2 + 1]);
        float nb = cB * (pb[tid * 2] + pb[tid * 2 + 1]);
        xhout[rr] = nh; xbout[rr] = nb;
        s1[rr] += nh;   s2[rr] += nb;   // exclusive row owner
    }
}

// ---------------------------------------------------------------------------
// y = C @ (s1 + s2); block = 4 waves = (2 rows x 2 K-halves). 512 blocks.
__global__ __launch_bounds__(256) void final_y(const float* __restrict__ C,
                                               const float* __restrict__ ws,
                                               float* __restrict__ out) {
    const float4* s14 = (const float4*)(ws + OFF_S1);
    const float4* s24 = (const float4*)(ws + OFF_S2);
    const int tid  = threadIdx.x;
    const int lane = tid & 63;
    const int w    = tid >> 6;
    const int rl   = w >> 1;
    const int hf   = w & 1;
    const int r    = blockIdx.x * 2 + rl;

    const float4* Crow = (const float4*)(C + (size_t)r * H);
    float acc = 0.f;
    #pragma unroll
    for (int i = 0; i < 4; ++i) {
        int f = hf * 256 + i * 64 + lane;
        float4 c = Crow[f];
        float4 a = s14[f], b = s24[f];
        acc = fmaf(c.x, a.x + b.x, acc);
        acc = fmaf(c.y, a.y + b.y, acc);
        acc = fmaf(c.z, a.z + b.z, acc);
        acc = fmaf(c.w, a.w + b.w, acc);
    }
    #pragma unroll
    for (int off = 32; off; off >>= 1) acc += __shfl_xor(acc, off, 64);

    __shared__ float pr[4];
    if (lane == 0) pr[w] = acc;
    __syncthreads();
    if (tid < 2) out[blockIdx.x * 2 + tid] = pr[tid * 2] + pr[tid * 2 + 1];
}

// ---------------------------------------------------------------------------
extern "C" void kernel_launch(void* const* d_in, const int* in_sizes, int n_in,
                              void* d_out, int out_size, void* d_ws, size_t ws_size,
                              hipStream_t stream) {
    const float* u  = (const float*)d_in[0];
    const float* du = (const float*)d_in[1];
    const float* W  = (const float*)d_in[2];
    const float* Bw = (const float*)d_in[3];
    const float* Cw = (const float*)d_in[4];
    const float* h  = (const float*)d_in[5];
    float* ws  = (float*)d_ws;
    float* out = (float*)d_out;

    build_init<<<NPAIRS + BU_BLOCKS, 256, 0, stream>>>(W, Bw, u, du, h, ws);

    const __half* Ah = (const __half*)d_ws;
    float* xh[2] = {ws + OFF_XH0, ws + OFF_XH1};
    float* xb[2] = {ws + OFF_XB0, ws + OFF_XB1};
    for (int k = 0; k < NT; ++k) {
        int a = k & 1, b = a ^ 1;
        matvec<<<1024, 256, 0, stream>>>(Ah,
                                         (const float4*)xh[a], (const float4*)xb[a],
                                         xh[b], xb[b],
                                         ws + OFF_S1, ws + OFF_S2,
                                         0.1f / (float)(k + 1), 0.1f / (float)(k + 2));
    }
    final_y<<<512, 256, 0, stream>>>(Cw, ws, out);
}